// Round 4
// baseline (201.698 us; speedup 1.0000x reference)
//
#include <hip/hip_runtime.h>

// YOLO loss. B=32, H=W=32, A=9, C=80, T=50, NET=512.
// 16 lanes per cell: lane l owns classes f = 5 + l + 16j (j=0..4); 80 = 5*16
// exactly. Each wave-instr reads 4 cells x 16 consecutive dwords = dense
// 64-B segments (fully coalesced, no LDS staging, no cache dependence).
// Block = 256 threads = 16 cells. Grid = 18432 blocks.

constexpr int NT = 50;

__global__ __launch_bounds__(256) void yolo_loss_kernel(
    const float* __restrict__ y_pred,     // (B,H,W,A,85) flat
    const float* __restrict__ y_true,     // (B,H,W,A,85)
    const float* __restrict__ true_boxes, // (B,50,4)
    const float* __restrict__ anchors,    // (9,2)
    float* __restrict__ out)              // (B,)
{
    __shared__ float s_tminx[NT], s_tminy[NT], s_tmaxx[NT], s_tmaxy[NT], s_tarea[NT];
    __shared__ float s_anch[18];
    __shared__ float s_red[4];

    const int tid  = threadIdx.x;
    const int lane = tid & 63;
    const int wid  = tid >> 6;

    const int cell0 = blockIdx.x * 16;       // 16 cells per block, same batch b
    const int b     = cell0 / 9216;          // 9216 = 32*32*9, divisible by 16

    if (tid < NT) {
        const float* tb = true_boxes + ((size_t)b * NT + tid) * 4;
        float tx = tb[0] * (1.0f / 32.0f);
        float ty = tb[1] * (1.0f / 32.0f);
        float tw = tb[2] * (1.0f / 512.0f);
        float th = tb[3] * (1.0f / 512.0f);
        s_tminx[tid] = tx - tw * 0.5f;
        s_tmaxx[tid] = tx + tw * 0.5f;
        s_tminy[tid] = ty - th * 0.5f;
        s_tmaxy[tid] = ty + th * 0.5f;
        s_tarea[tid] = tw * th;
    }
    if (tid < 18) s_anch[tid] = anchors[tid];
    __syncthreads();

    const int l16 = lane & 15;                // lane within 16-lane cell group
    const int gb  = lane & ~15;               // group base lane in wave
    const int cell = cell0 + (tid >> 4);
    const int local = cell - b * 9216;
    const int a = local % 9;
    const int w = (local / 9) % 32;
    const int h = local / 288;

    const size_t cbase = (size_t)cell * 85;

    // ---- 12 independent, fully-coalesced loads ----
    float pc[5], tc[5];
    #pragma unroll
    for (int j = 0; j < 5; ++j) {
        pc[j] = y_pred[cbase + 5 + l16 + 16 * j];
        tc[j] = y_true[cbase + 5 + l16 + 16 * j];
    }
    float bxp = 0.0f, bxt = 0.0f;
    if (l16 < 5) {
        bxp = y_pred[cbase + l16];
        bxt = y_true[cbase + l16];
    }

    // ---- broadcast box fields to all 16 lanes of the group ----
    const float p0 = __shfl(bxp, gb + 0), p1 = __shfl(bxp, gb + 1);
    const float p2 = __shfl(bxp, gb + 2), p3 = __shfl(bxp, gb + 3);
    const float p4 = __shfl(bxp, gb + 4);
    const float t0 = __shfl(bxt, gb + 0), t1 = __shfl(bxt, gb + 1);
    const float t2 = __shfl(bxt, gb + 2), t3 = __shfl(bxt, gb + 3);
    const float t4 = __shfl(bxt, gb + 4);

    const float aw = s_anch[a * 2 + 0];
    const float ah = s_anch[a * 2 + 1];

    // ---- per-cell geometry (redundant across the 16 lanes — cheap) ----
    const float sig0  = 1.0f / (1.0f + __expf(-p0));
    const float sig1  = 1.0f / (1.0f + __expf(-p1));
    const float predx = (float)w + sig0;
    const float predy = (float)h + sig1;
    const float pconf = 1.0f / (1.0f + __expf(-p4));

    const float px = predx * (1.0f / 32.0f);
    const float py = predy * (1.0f / 32.0f);
    const float pw = __expf(p2) * aw * (1.0f / 512.0f);
    const float ph = __expf(p3) * ah * (1.0f / 512.0f);
    const float pminx = px - pw * 0.5f, pmaxx = px + pw * 0.5f;
    const float pminy = py - ph * 0.5f, pmaxy = py + ph * 0.5f;
    const float parea = pw * ph;

    // ---- IoU ignore flag: 3-4 boxes per lane; OR across 16 lanes ----
    // best_iou >= 0.5  <=>  exists t: 2*inter >= union (union > 0 always)
    int ig = 0;
    #pragma unroll
    for (int k = 0; k < 4; ++k) {
        const int box = l16 + 16 * k;
        if (box < NT) {
            float iw = fminf(pmaxx, s_tmaxx[box]) - fmaxf(pminx, s_tminx[box]);
            float ih = fminf(pmaxy, s_tmaxy[box]) - fmaxf(pminy, s_tminy[box]);
            iw = fmaxf(iw, 0.0f);
            ih = fmaxf(ih, 0.0f);
            float inter = iw * ih;
            float uni   = parea + s_tarea[box] - inter;
            ig |= (2.0f * inter >= uni) ? 1 : 0;
        }
    }

    // ---- classes: per-lane scan of 5, then 16-lane butterfly combines ----
    float tmax = tc[0], p_at = pc[0], pmax = pc[0];
    int   tidx = l16;
    #pragma unroll
    for (int j = 1; j < 5; ++j) {
        pmax = fmaxf(pmax, pc[j]);
        if (tc[j] > tmax) { tmax = tc[j]; p_at = pc[j]; tidx = l16 + 16 * j; }
    }
    #pragma unroll
    for (int d = 1; d < 16; d <<= 1) {
        const float ot = __shfl_xor(tmax, d);
        const float op = __shfl_xor(p_at, d);
        const int   oi = __shfl_xor(tidx, d);
        const bool upd = (ot > tmax) || (ot == tmax && oi < tidx);
        tmax = upd ? ot : tmax;
        p_at = upd ? op : p_at;
        tidx = upd ? oi : tidx;
        pmax = fmaxf(pmax, __shfl_xor(pmax, d));
        ig  |= __shfl_xor(ig, d);
    }

    float sum = (__expf(pc[0] - pmax) + __expf(pc[1] - pmax)) +
                (__expf(pc[2] - pmax) + __expf(pc[3] - pmax)) +
                 __expf(pc[4] - pmax);
    #pragma unroll
    for (int d = 1; d < 16; d <<= 1) sum += __shfl_xor(sum, d);
    const float ce = (pmax + __logf(sum)) - p_at;

    // ---- deltas ----
    const float om  = t4;
    const float ew  = __expf(t2) * aw * (1.0f / 512.0f);
    const float eh  = __expf(t3) * ah * (1.0f / 512.0f);
    const float whs = 2.0f - ew * eh;

    const float xyd0 = om * (predx - t0) * whs;
    const float xyd1 = om * (predy - t1) * whs;
    const float whd0 = om * (p2 - t2) * whs;
    const float whd1 = om * (p3 - t3) * whs;
    const float cd   = om * (pconf - t4) * 5.0f + (1.0f - om) * (ig ? 0.0f : pconf);

    float partial = xyd0 * xyd0 + xyd1 * xyd1 + whd0 * whd0 + whd1 * whd1 +
                    cd * cd + om * ce;

    // ---- group leader emits; sum 4 groups across the wave; block reduce ----
    partial = (l16 == 0) ? partial : 0.0f;
    partial += __shfl_xor(partial, 16);
    partial += __shfl_xor(partial, 32);

    if (lane == 0) s_red[wid] = partial;
    __syncthreads();
    if (tid == 0)
        atomicAdd(&out[b], s_red[0] + s_red[1] + s_red[2] + s_red[3]);
}

extern "C" void kernel_launch(void* const* d_in, const int* in_sizes, int n_in,
                              void* d_out, int out_size, void* d_ws, size_t ws_size,
                              hipStream_t stream) {
    // setup_inputs order: input_image (unused), y_pred, y_true, true_boxes, anchors
    const float* y_pred     = (const float*)d_in[1];
    const float* y_true     = (const float*)d_in[2];
    const float* true_boxes = (const float*)d_in[3];
    const float* anchors    = (const float*)d_in[4];
    float* out = (float*)d_out;

    hipMemsetAsync(d_out, 0, (size_t)out_size * sizeof(float), stream);

    dim3 grid(294912 / 16);   // 18432 blocks, 16 cells each
    yolo_loss_kernel<<<grid, 256, 0, stream>>>(y_pred, y_true, true_boxes, anchors, out);
}